// Round 1
// baseline (723.708 us; speedup 1.0000x reference)
//
#include <hip/hip_runtime.h>
#include <hip/hip_bf16.h>

#define N_NODES 50000
#define N_EDGES 800000

static inline int cdiv(int a, int b) { return (a + b - 1) / b; }

// ---------------- CSR build ----------------

__global__ void hist_kernel(const int* __restrict__ row, int* __restrict__ counts, int E) {
    int e = blockIdx.x * 256 + threadIdx.x;
    if (e < E) atomicAdd(&counts[row[e]], 1);
}

// single-block exclusive scan over counts[n] -> row_ptr[n+1]
__global__ void scan_kernel(const int* __restrict__ counts, int* __restrict__ row_ptr, int n) {
    __shared__ int sums[1024];
    int tid = threadIdx.x;
    int chunk = (n + 1023) / 1024;
    int start = tid * chunk;
    int end = start + chunk; if (end > n) end = n;
    int s = 0;
    for (int i = start; i < end; ++i) s += counts[i];
    sums[tid] = s;
    __syncthreads();
    for (int off = 1; off < 1024; off <<= 1) {
        int t = (tid >= off) ? sums[tid - off] : 0;
        __syncthreads();
        sums[tid] += t;
        __syncthreads();
    }
    int carry = sums[tid] - s;  // exclusive prefix of this thread's chunk
    for (int i = start; i < end; ++i) {
        row_ptr[i] = carry;
        carry += counts[i];
    }
    if (tid == 1023) row_ptr[n] = carry;  // total
}

__global__ void scatter_kernel(const int* __restrict__ row, const int* __restrict__ col,
                               const float* __restrict__ vals, const int* __restrict__ row_ptr,
                               int* __restrict__ cursor, int* __restrict__ ecol,
                               float* __restrict__ eval, int E) {
    int e = blockIdx.x * 256 + threadIdx.x;
    if (e < E) {
        int r = row[e];
        int pos = row_ptr[r] + atomicAdd(&cursor[r], 1);
        ecol[pos] = col[e];
        eval[pos] = vals[e];
    }
}

// ---------------- fp32 register-tiled GEMM ----------------
// C[M,BN-wide] = op(A[M,K] @ W[K,BN] (+bias) (relu)), BN == full N of this matmul.
template <int BM, int BN, int BK, int TM, int TN, bool RELU, bool BIAS>
__global__ __launch_bounds__((BM / TM) * (BN / TN))
void gemm_kernel(const float* __restrict__ A, int lda,
                 const float* __restrict__ W, int ldw,
                 const float* __restrict__ bias,
                 float* __restrict__ C, int ldc,
                 int M, int K) {
    constexpr int THREADS = (BM / TM) * (BN / TN);
    __shared__ float As[BK][BM + 1];   // k-major, padded
    __shared__ float Ws[BK][BN];
    const int tid = threadIdx.x;
    const int tcol = tid % (BN / TN);
    const int trow = tid / (BN / TN);
    const int rowBase = blockIdx.x * BM;

    float acc[TM][TN] = {};

    for (int k0 = 0; k0 < K; k0 += BK) {
        // stage A tile (BM x BK), transposed into As[k][row]
        constexpr int A_F4 = BM * BK / 4 / THREADS;
#pragma unroll
        for (int i = 0; i < A_F4; ++i) {
            int idx = tid + i * THREADS;          // float4 index
            int r = idx / (BK / 4);
            int kk = (idx % (BK / 4)) * 4;
            float4 v = {0.f, 0.f, 0.f, 0.f};
            int gr = rowBase + r;
            if (gr < M) v = *(const float4*)&A[(size_t)gr * lda + k0 + kk];
            As[kk + 0][r] = v.x; As[kk + 1][r] = v.y;
            As[kk + 2][r] = v.z; As[kk + 3][r] = v.w;
        }
        // stage W tile (BK x BN), same layout
        constexpr int W_F4 = BK * BN / 4 / THREADS;
#pragma unroll
        for (int i = 0; i < W_F4; ++i) {
            int idx = tid + i * THREADS;
            int kk = idx / (BN / 4);
            int c = (idx % (BN / 4)) * 4;
            *(float4*)&Ws[kk][c] = *(const float4*)&W[(size_t)(k0 + kk) * ldw + c];
        }
        __syncthreads();
#pragma unroll
        for (int k = 0; k < BK; ++k) {
            float a[TM], w[TN];
#pragma unroll
            for (int i = 0; i < TM; ++i) a[i] = As[k][trow * TM + i];
#pragma unroll
            for (int j = 0; j < TN; ++j) w[j] = Ws[k][tcol * TN + j];
#pragma unroll
            for (int i = 0; i < TM; ++i)
#pragma unroll
                for (int j = 0; j < TN; ++j) acc[i][j] += a[i] * w[j];
        }
        __syncthreads();
    }

#pragma unroll
    for (int i = 0; i < TM; ++i) {
        int gr = rowBase + trow * TM + i;
        if (gr >= M) continue;
#pragma unroll
        for (int j0 = 0; j0 < TN; j0 += 4) {
            int c = tcol * TN + j0;
            float4 v;
            v.x = acc[i][j0 + 0]; v.y = acc[i][j0 + 1];
            v.z = acc[i][j0 + 2]; v.w = acc[i][j0 + 3];
            if (BIAS) {
                v.x += bias[c + 0]; v.y += bias[c + 1];
                v.z += bias[c + 2]; v.w += bias[c + 3];
            }
            if (RELU) {
                v.x = fmaxf(v.x, 0.f); v.y = fmaxf(v.y, 0.f);
                v.z = fmaxf(v.z, 0.f); v.w = fmaxf(v.w, 0.f);
            }
            *(float4*)&C[(size_t)gr * ldc + c] = v;
        }
    }
}

// ---------------- SpMM: out[node] = relu(sum_e val*support[col] + b) ----------------
// one wave per node; each lane owns 2 of the 128 dims
__global__ __launch_bounds__(256)
void spmm_kernel(const int* __restrict__ row_ptr, const int* __restrict__ ecol,
                 const float* __restrict__ eval, const float* __restrict__ support,
                 const float* __restrict__ bias, float* __restrict__ out,
                 int ldo, int n) {
    int wave = threadIdx.x >> 6;
    int lane = threadIdx.x & 63;
    int node = blockIdx.x * 4 + wave;
    if (node >= n) return;
    int start = row_ptr[node], end = row_ptr[node + 1];
    float2 acc = {0.f, 0.f};
    for (int p = start; p < end; ++p) {
        int c = ecol[p];
        float v = eval[p];
        float2 s = *(const float2*)&support[(size_t)c * 128 + lane * 2];
        acc.x += v * s.x;
        acc.y += v * s.y;
    }
    float b0 = bias[lane * 2], b1 = bias[lane * 2 + 1];
    out[(size_t)node * ldo + lane * 2 + 0] = fmaxf(acc.x + b0, 0.f);
    out[(size_t)node * ldo + lane * 2 + 1] = fmaxf(acc.y + b1, 0.f);
}

// ---------------- final 64->2 layer ----------------
__global__ __launch_bounds__(256)
void fc3_kernel(const float* __restrict__ h2, const float* __restrict__ W,
                const float* __restrict__ b, float* __restrict__ out, int M) {
    __shared__ float Ws[128];
    if (threadIdx.x < 128) Ws[threadIdx.x] = W[threadIdx.x];
    __syncthreads();
    int nid = blockIdx.x * blockDim.x + threadIdx.x;
    if (nid >= M) return;
    float a0 = b[0], a1 = b[1];
    const float4* hp = (const float4*)(h2 + (size_t)nid * 64);
#pragma unroll
    for (int k4 = 0; k4 < 16; ++k4) {
        float4 v = hp[k4];
        int k = k4 * 4;
        a0 += v.x * Ws[(k + 0) * 2 + 0] + v.y * Ws[(k + 1) * 2 + 0]
            + v.z * Ws[(k + 2) * 2 + 0] + v.w * Ws[(k + 3) * 2 + 0];
        a1 += v.x * Ws[(k + 0) * 2 + 1] + v.y * Ws[(k + 1) * 2 + 1]
            + v.z * Ws[(k + 2) * 2 + 1] + v.w * Ws[(k + 3) * 2 + 1];
    }
    out[(size_t)nid * 2 + 0] = a0;
    out[(size_t)nid * 2 + 1] = a1;
}

extern "C" void kernel_launch(void* const* d_in, const int* in_sizes, int n_in,
                              void* d_out, int out_size, void* d_ws, size_t ws_size,
                              hipStream_t stream) {
    const int*   adj_row  = (const int*)d_in[0];
    const int*   adj_col  = (const int*)d_in[1];
    const float* adj_vals = (const float*)d_in[2];
    const float* x        = (const float*)d_in[3];
    // d_in[4] graph_indicator: unused by reference
    const float* W1   = (const float*)d_in[5];
    const float* b1   = (const float*)d_in[6];
    const float* W2   = (const float*)d_in[7];
    const float* b2   = (const float*)d_in[8];
    const float* W3   = (const float*)d_in[9];
    const float* b3   = (const float*)d_in[10];
    const float* fcW1 = (const float*)d_in[11];
    const float* fcb1 = (const float*)d_in[12];
    const float* fcW2 = (const float*)d_in[13];
    const float* fcb2 = (const float*)d_in[14];
    const float* fcW3 = (const float*)d_in[15];
    const float* fcb3 = (const float*)d_in[16];
    float* out = (float*)d_out;

    const int N = N_NODES, E = N_EDGES;

    // workspace carve (256B aligned)
    char* p = (char*)d_ws;
    auto alloc = [&](size_t bytes) {
        char* q = p;
        p += (bytes + 255) & ~(size_t)255;
        return q;
    };
    float* feat    = (float*)alloc((size_t)N * 384 * 4);  // g1|g2|g3 columns
    float* support = (float*)alloc((size_t)N * 128 * 4);  // also h1 after fc1
    int*   row_ptr = (int*)alloc((size_t)(N + 1) * 4);
    int*   cursor  = (int*)alloc((size_t)N * 4);
    int*   ecol    = (int*)alloc((size_t)E * 4);
    float* eval    = (float*)alloc((size_t)E * 4);
    float* h1 = support;   // safe alias: support dead after 3rd spmm
    float* h2 = feat;      // safe alias: feat dead after fc1

    // ---- CSR build (reused by all 3 layers) ----
    hipMemsetAsync(cursor, 0, (size_t)N * 4, stream);
    hist_kernel<<<cdiv(E, 256), 256, 0, stream>>>(adj_row, cursor, E);
    scan_kernel<<<1, 1024, 0, stream>>>(cursor, row_ptr, N);
    hipMemsetAsync(cursor, 0, (size_t)N * 4, stream);
    scatter_kernel<<<cdiv(E, 256), 256, 0, stream>>>(adj_row, adj_col, adj_vals,
                                                     row_ptr, cursor, ecol, eval, E);

    const int gemmGrid = cdiv(N, 64);
    const int spmmGrid = cdiv(N, 4);

    // ---- GCN layer 1 ----
    gemm_kernel<64, 128, 32, 4, 8, false, false><<<gemmGrid, 256, 0, stream>>>(
        x, 128, W1, 128, nullptr, support, 128, N, 128);
    spmm_kernel<<<spmmGrid, 256, 0, stream>>>(row_ptr, ecol, eval, support, b1,
                                              feat + 0, 384, N);
    // ---- GCN layer 2 ----
    gemm_kernel<64, 128, 32, 4, 8, false, false><<<gemmGrid, 256, 0, stream>>>(
        feat + 0, 384, W2, 128, nullptr, support, 128, N, 128);
    spmm_kernel<<<spmmGrid, 256, 0, stream>>>(row_ptr, ecol, eval, support, b2,
                                              feat + 128, 384, N);
    // ---- GCN layer 3 ----
    gemm_kernel<64, 128, 32, 4, 8, false, false><<<gemmGrid, 256, 0, stream>>>(
        feat + 128, 384, W3, 128, nullptr, support, 128, N, 128);
    spmm_kernel<<<spmmGrid, 256, 0, stream>>>(row_ptr, ecol, eval, support, b3,
                                              feat + 256, 384, N);

    // ---- fc1: relu(feat[50000,384] @ fcW1[384,128] + fcb1) -> h1 ----
    gemm_kernel<64, 128, 32, 4, 8, true, true><<<gemmGrid, 256, 0, stream>>>(
        feat, 384, fcW1, 128, fcb1, h1, 128, N, 384);
    // ---- fc2: relu(h1 @ fcW2[128,64] + fcb2) -> h2 ----
    gemm_kernel<64, 64, 32, 4, 4, true, true><<<gemmGrid, 256, 0, stream>>>(
        h1, 128, fcW2, 64, fcb2, h2, 64, N, 128);
    // ---- fc3: h2 @ fcW3[64,2] + fcb3 -> out ----
    fc3_kernel<<<cdiv(N, 256), 256, 0, stream>>>(h2, fcW3, fcb3, out, N);
}

// Round 2
// 629.122 us; speedup vs baseline: 1.1503x; 1.1503x over previous
//
#include <hip/hip_runtime.h>
#include <hip/hip_bf16.h>

#define N_NODES 50000
#define N_EDGES 800000

static inline int cdiv(int a, int b) { return (a + b - 1) / b; }

// ---------------- CSR build ----------------

__global__ void hist_kernel(const int* __restrict__ row, int* __restrict__ counts, int E) {
    int e = blockIdx.x * 256 + threadIdx.x;
    if (e < E) atomicAdd(&counts[row[e]], 1);
}

// single-block exclusive scan over counts[n] -> row_ptr[n+1]
__global__ void scan_kernel(const int* __restrict__ counts, int* __restrict__ row_ptr, int n) {
    __shared__ int sums[1024];
    int tid = threadIdx.x;
    int chunk = (n + 1023) / 1024;
    int start = tid * chunk;
    int end = start + chunk; if (end > n) end = n;
    int s = 0;
    for (int i = start; i < end; ++i) s += counts[i];
    sums[tid] = s;
    __syncthreads();
    for (int off = 1; off < 1024; off <<= 1) {
        int t = (tid >= off) ? sums[tid - off] : 0;
        __syncthreads();
        sums[tid] += t;
        __syncthreads();
    }
    int carry = sums[tid] - s;  // exclusive prefix of this thread's chunk
    for (int i = start; i < end; ++i) {
        row_ptr[i] = carry;
        carry += counts[i];
    }
    if (tid == 1023) row_ptr[n] = carry;  // total
}

__global__ void scatter_kernel(const int* __restrict__ row, const int* __restrict__ col,
                               const float* __restrict__ vals, const int* __restrict__ row_ptr,
                               int* __restrict__ cursor, int* __restrict__ ecol,
                               float* __restrict__ eval, int E) {
    int e = blockIdx.x * 256 + threadIdx.x;
    if (e < E) {
        int r = row[e];
        int pos = row_ptr[r] + atomicAdd(&cursor[r], 1);
        ecol[pos] = col[e];
        eval[pos] = vals[e];
    }
}

// ---------------- fp32 register-tiled GEMM, vectorized LDS ----------------
// TM must be 4; TN in {4,8}. As padded to BM+4 so rows stay 16B-aligned.
template <int BM, int BN, int BK, int TM, int TN, bool RELU, bool BIAS>
__global__ __launch_bounds__((BM / TM) * (BN / TN), 4)
void gemm_kernel(const float* __restrict__ A, int lda,
                 const float* __restrict__ W, int ldw,
                 const float* __restrict__ bias,
                 float* __restrict__ C, int ldc,
                 int M, int K) {
    constexpr int THREADS = (BM / TM) * (BN / TN);
    static_assert(TM == 4, "TM must be 4 for float4 LDS reads");
    __shared__ float As[BK][BM + 4];   // k-major; +4 keeps every row 16B aligned
    __shared__ float Ws[BK][BN];
    const int tid = threadIdx.x;
    const int tcol = tid % (BN / TN);
    const int trow = tid / (BN / TN);
    const int rowBase = blockIdx.x * BM;

    float acc[TM][TN] = {};

    for (int k0 = 0; k0 < K; k0 += BK) {
        // stage A tile (BM x BK) transposed into As[k][row]
        constexpr int A_F4 = BM * BK / 4 / THREADS;
#pragma unroll
        for (int i = 0; i < A_F4; ++i) {
            int idx = tid + i * THREADS;          // float4 index
            int r = idx / (BK / 4);
            int kk = (idx % (BK / 4)) * 4;
            float4 v = {0.f, 0.f, 0.f, 0.f};
            int gr = rowBase + r;
            if (gr < M) v = *(const float4*)&A[(size_t)gr * lda + k0 + kk];
            As[kk + 0][r] = v.x; As[kk + 1][r] = v.y;
            As[kk + 2][r] = v.z; As[kk + 3][r] = v.w;
        }
        // stage W tile (BK x BN)
        constexpr int W_F4 = BK * BN / 4 / THREADS;
#pragma unroll
        for (int i = 0; i < W_F4; ++i) {
            int idx = tid + i * THREADS;
            int kk = idx / (BN / 4);
            int c = (idx % (BN / 4)) * 4;
            *(float4*)&Ws[kk][c] = *(const float4*)&W[(size_t)(k0 + kk) * ldw + c];
        }
        __syncthreads();
#pragma unroll
        for (int k = 0; k < BK; ++k) {
            float4 av = *(const float4*)&As[k][trow * 4];
            float a[4] = {av.x, av.y, av.z, av.w};
            float w[TN];
#pragma unroll
            for (int j4 = 0; j4 < TN / 4; ++j4) {
                float4 wv = *(const float4*)&Ws[k][tcol * TN + j4 * 4];
                w[j4 * 4 + 0] = wv.x; w[j4 * 4 + 1] = wv.y;
                w[j4 * 4 + 2] = wv.z; w[j4 * 4 + 3] = wv.w;
            }
#pragma unroll
            for (int i = 0; i < TM; ++i)
#pragma unroll
                for (int j = 0; j < TN; ++j) acc[i][j] += a[i] * w[j];
        }
        __syncthreads();
    }

#pragma unroll
    for (int i = 0; i < TM; ++i) {
        int gr = rowBase + trow * TM + i;
        if (gr >= M) continue;
#pragma unroll
        for (int j0 = 0; j0 < TN; j0 += 4) {
            int c = tcol * TN + j0;
            float4 v;
            v.x = acc[i][j0 + 0]; v.y = acc[i][j0 + 1];
            v.z = acc[i][j0 + 2]; v.w = acc[i][j0 + 3];
            if (BIAS) {
                v.x += bias[c + 0]; v.y += bias[c + 1];
                v.z += bias[c + 2]; v.w += bias[c + 3];
            }
            if (RELU) {
                v.x = fmaxf(v.x, 0.f); v.y = fmaxf(v.y, 0.f);
                v.z = fmaxf(v.z, 0.f); v.w = fmaxf(v.w, 0.f);
            }
            *(float4*)&C[(size_t)gr * ldc + c] = v;
        }
    }
}

// ---------------- SpMM: out[node] = relu(sum_e val*support[col] + b) ----------------
// 32 lanes per node (each owns 4 of 128 dims, float4 gathers); 2 nodes per wave,
// 8 nodes per 256-thread block. Edge loop unrolled x2 for outstanding loads.
__global__ __launch_bounds__(256)
void spmm_kernel(const int* __restrict__ row_ptr, const int* __restrict__ ecol,
                 const float* __restrict__ eval, const float* __restrict__ support,
                 const float* __restrict__ bias, float* __restrict__ out,
                 int ldo, int n) {
    int t = threadIdx.x;
    int sub = t >> 5;        // 0..7: node slot within block
    int lane32 = t & 31;
    int node = blockIdx.x * 8 + sub;
    if (node >= n) return;
    int start = row_ptr[node], end = row_ptr[node + 1];
    float4 acc = {0.f, 0.f, 0.f, 0.f};
    int p = start;
    for (; p + 2 <= end; p += 2) {
        int c0 = ecol[p], c1 = ecol[p + 1];
        float v0 = eval[p], v1 = eval[p + 1];
        float4 s0 = *(const float4*)&support[(size_t)c0 * 128 + lane32 * 4];
        float4 s1 = *(const float4*)&support[(size_t)c1 * 128 + lane32 * 4];
        acc.x += v0 * s0.x; acc.y += v0 * s0.y;
        acc.z += v0 * s0.z; acc.w += v0 * s0.w;
        acc.x += v1 * s1.x; acc.y += v1 * s1.y;
        acc.z += v1 * s1.z; acc.w += v1 * s1.w;
    }
    if (p < end) {
        int c0 = ecol[p];
        float v0 = eval[p];
        float4 s0 = *(const float4*)&support[(size_t)c0 * 128 + lane32 * 4];
        acc.x += v0 * s0.x; acc.y += v0 * s0.y;
        acc.z += v0 * s0.z; acc.w += v0 * s0.w;
    }
    float4 b = *(const float4*)&bias[lane32 * 4];
    float4 o;
    o.x = fmaxf(acc.x + b.x, 0.f);
    o.y = fmaxf(acc.y + b.y, 0.f);
    o.z = fmaxf(acc.z + b.z, 0.f);
    o.w = fmaxf(acc.w + b.w, 0.f);
    *(float4*)&out[(size_t)node * ldo + lane32 * 4] = o;
}

// ---------------- final 64->2 layer ----------------
__global__ __launch_bounds__(256)
void fc3_kernel(const float* __restrict__ h2, const float* __restrict__ W,
                const float* __restrict__ b, float* __restrict__ out, int M) {
    __shared__ float Ws[128];
    if (threadIdx.x < 128) Ws[threadIdx.x] = W[threadIdx.x];
    __syncthreads();
    int nid = blockIdx.x * blockDim.x + threadIdx.x;
    if (nid >= M) return;
    float a0 = b[0], a1 = b[1];
    const float4* hp = (const float4*)(h2 + (size_t)nid * 64);
#pragma unroll
    for (int k4 = 0; k4 < 16; ++k4) {
        float4 v = hp[k4];
        int k = k4 * 4;
        a0 += v.x * Ws[(k + 0) * 2 + 0] + v.y * Ws[(k + 1) * 2 + 0]
            + v.z * Ws[(k + 2) * 2 + 0] + v.w * Ws[(k + 3) * 2 + 0];
        a1 += v.x * Ws[(k + 0) * 2 + 1] + v.y * Ws[(k + 1) * 2 + 1]
            + v.z * Ws[(k + 2) * 2 + 1] + v.w * Ws[(k + 3) * 2 + 1];
    }
    out[(size_t)nid * 2 + 0] = a0;
    out[(size_t)nid * 2 + 1] = a1;
}

extern "C" void kernel_launch(void* const* d_in, const int* in_sizes, int n_in,
                              void* d_out, int out_size, void* d_ws, size_t ws_size,
                              hipStream_t stream) {
    const int*   adj_row  = (const int*)d_in[0];
    const int*   adj_col  = (const int*)d_in[1];
    const float* adj_vals = (const float*)d_in[2];
    const float* x        = (const float*)d_in[3];
    // d_in[4] graph_indicator: unused by reference
    const float* W1   = (const float*)d_in[5];
    const float* b1   = (const float*)d_in[6];
    const float* W2   = (const float*)d_in[7];
    const float* b2   = (const float*)d_in[8];
    const float* W3   = (const float*)d_in[9];
    const float* b3   = (const float*)d_in[10];
    const float* fcW1 = (const float*)d_in[11];
    const float* fcb1 = (const float*)d_in[12];
    const float* fcW2 = (const float*)d_in[13];
    const float* fcb2 = (const float*)d_in[14];
    const float* fcW3 = (const float*)d_in[15];
    const float* fcb3 = (const float*)d_in[16];
    float* out = (float*)d_out;

    const int N = N_NODES, E = N_EDGES;

    // workspace carve (256B aligned)
    char* p = (char*)d_ws;
    auto alloc = [&](size_t bytes) {
        char* q = p;
        p += (bytes + 255) & ~(size_t)255;
        return q;
    };
    float* feat    = (float*)alloc((size_t)N * 384 * 4);  // g1|g2|g3 columns
    float* support = (float*)alloc((size_t)N * 128 * 4);  // also h1 after fc1
    int*   row_ptr = (int*)alloc((size_t)(N + 1) * 4);
    int*   cursor  = (int*)alloc((size_t)N * 4);
    int*   ecol    = (int*)alloc((size_t)E * 4);
    float* eval    = (float*)alloc((size_t)E * 4);
    float* h1 = support;   // safe alias: support dead after 3rd spmm
    float* h2 = feat;      // safe alias: feat dead after fc1

    // ---- CSR build (reused by all 3 layers) ----
    hipMemsetAsync(cursor, 0, (size_t)N * 4, stream);
    hist_kernel<<<cdiv(E, 256), 256, 0, stream>>>(adj_row, cursor, E);
    scan_kernel<<<1, 1024, 0, stream>>>(cursor, row_ptr, N);
    hipMemsetAsync(cursor, 0, (size_t)N * 4, stream);
    scatter_kernel<<<cdiv(E, 256), 256, 0, stream>>>(adj_row, adj_col, adj_vals,
                                                     row_ptr, cursor, ecol, eval, E);

    const int gemmGrid = cdiv(N, 64);
    const int spmmGrid = cdiv(N, 8);

    // ---- GCN layer 1 ----
    gemm_kernel<64, 128, 32, 4, 8, false, false><<<gemmGrid, 256, 0, stream>>>(
        x, 128, W1, 128, nullptr, support, 128, N, 128);
    spmm_kernel<<<spmmGrid, 256, 0, stream>>>(row_ptr, ecol, eval, support, b1,
                                              feat + 0, 384, N);
    // ---- GCN layer 2 ----
    gemm_kernel<64, 128, 32, 4, 8, false, false><<<gemmGrid, 256, 0, stream>>>(
        feat + 0, 384, W2, 128, nullptr, support, 128, N, 128);
    spmm_kernel<<<spmmGrid, 256, 0, stream>>>(row_ptr, ecol, eval, support, b2,
                                              feat + 128, 384, N);
    // ---- GCN layer 3 ----
    gemm_kernel<64, 128, 32, 4, 8, false, false><<<gemmGrid, 256, 0, stream>>>(
        feat + 128, 384, W3, 128, nullptr, support, 128, N, 128);
    spmm_kernel<<<spmmGrid, 256, 0, stream>>>(row_ptr, ecol, eval, support, b3,
                                              feat + 256, 384, N);

    // ---- fc1: relu(feat[50000,384] @ fcW1[384,128] + fcb1) -> h1 ----
    gemm_kernel<64, 128, 32, 4, 8, true, true><<<gemmGrid, 256, 0, stream>>>(
        feat, 384, fcW1, 128, fcb1, h1, 128, N, 384);
    // ---- fc2: relu(h1 @ fcW2[128,64] + fcb2) -> h2 ----
    gemm_kernel<64, 64, 32, 4, 4, true, true><<<gemmGrid, 256, 0, stream>>>(
        h1, 128, fcW2, 64, fcb2, h2, 64, N, 128);
    // ---- fc3: h2 @ fcW3[64,2] + fcb3 -> out ----
    fc3_kernel<<<cdiv(N, 256), 256, 0, stream>>>(h2, fcW3, fcb3, out, N);
}

// Round 3
// 460.740 us; speedup vs baseline: 1.5708x; 1.3655x over previous
//
#include <hip/hip_runtime.h>
#include <hip/hip_bf16.h>

#define N_NODES 50000
#define N_EDGES 800000

static inline int cdiv(int a, int b) { return (a + b - 1) / b; }

typedef __attribute__((ext_vector_type(8))) short short8;
typedef __attribute__((ext_vector_type(4))) float f32x4;

__device__ __forceinline__ float b2f(unsigned short u) {
    union { unsigned int i; float f; } c;
    c.i = ((unsigned int)u) << 16;
    return c.f;
}

// ---------------- CSR build ----------------

__global__ void hist_kernel(const int* __restrict__ row, int* __restrict__ counts, int E) {
    int e = blockIdx.x * 256 + threadIdx.x;
    if (e < E) atomicAdd(&counts[row[e]], 1);
}

__global__ void scan_kernel(const int* __restrict__ counts, int* __restrict__ row_ptr, int n) {
    __shared__ int sums[1024];
    int tid = threadIdx.x;
    int chunk = (n + 1023) / 1024;
    int start = tid * chunk;
    int end = start + chunk; if (end > n) end = n;
    if (start > n) start = n;
    int s = 0;
    for (int i = start; i < end; ++i) s += counts[i];
    sums[tid] = s;
    __syncthreads();
    for (int off = 1; off < 1024; off <<= 1) {
        int t = (tid >= off) ? sums[tid - off] : 0;
        __syncthreads();
        sums[tid] += t;
        __syncthreads();
    }
    int carry = sums[tid] - s;
    for (int i = start; i < end; ++i) {
        row_ptr[i] = carry;
        carry += counts[i];
    }
    if (tid == 1023) row_ptr[n] = carry;
}

__global__ void scatter_kernel(const int* __restrict__ row, const int* __restrict__ col,
                               const float* __restrict__ vals, const int* __restrict__ row_ptr,
                               int* __restrict__ cursor, int* __restrict__ ecol,
                               float* __restrict__ eval, int E) {
    int e = blockIdx.x * 256 + threadIdx.x;
    if (e < E) {
        int r = row[e];
        int pos = row_ptr[r] + atomicAdd(&cursor[r], 1);
        ecol[pos] = col[e];
        eval[pos] = vals[e];
    }
}

// ---------------- converts / packing ----------------

__global__ void f2b_kernel(const float* __restrict__ in, __hip_bfloat16* __restrict__ out, int n) {
    int i = (blockIdx.x * 256 + threadIdx.x) * 4;
    if (i >= n) return;
    float4 v = *(const float4*)&in[i];
    __hip_bfloat16 h[4] = {__float2bfloat16(v.x), __float2bfloat16(v.y),
                           __float2bfloat16(v.z), __float2bfloat16(v.w)};
    *(ushort2*)&out[i] = *(ushort2*)&h[0];
    *(ushort2*)&out[i + 2] = *(ushort2*)&h[2];
}

// pack fp32 W[K,N] row-major into B-fragment order for mfma_f32_16x16x32_bf16:
// frag element j of lane l for (n-tile nt, k-chunk kc) = W[kc*32 + (l>>4)*8 + j][nt*16 + (l&15)]
// stored at out[(((nt*(K/32)) + kc)*64 + l)*8 + j]
__global__ void pack_w_kernel(const float* __restrict__ W, __hip_bfloat16* __restrict__ out,
                              int K, int N) {
    int t = blockIdx.x * 256 + threadIdx.x;
    int total = (N / 16) * (K / 32) * 64;
    if (t >= total) return;
    int lane = t & 63;
    int kc = (t >> 6) % (K / 32);
    int nt = (t >> 6) / (K / 32);
    int kbase = kc * 32 + (lane >> 4) * 8;
    int col = nt * 16 + (lane & 15);
    __hip_bfloat16* dst = out + (size_t)t * 8;
#pragma unroll
    for (int j = 0; j < 8; ++j)
        dst[j] = __float2bfloat16(W[(size_t)(kbase + j) * N + col]);
}

// ---------------- bf16 MFMA GEMM ----------------
// C[M,N] = op(A[M,KTOT] @ W) with W pre-packed. Block: 64 rows x N cols, 256 threads (4 waves).
// N==128: wave handles 32 cols (2 n-tiles); N==64: 16 cols (1 n-tile).
template <int KTOT, int N, bool RELU, bool BIAS>
__global__ __launch_bounds__(256, 3)
void mfma_gemm(const __hip_bfloat16* __restrict__ A, int lda,
               const __hip_bfloat16* __restrict__ pW,
               const float* __restrict__ bias,
               __hip_bfloat16* __restrict__ C, int ldc, int M) {
    constexpr int NS = (N == 128) ? 2 : 1;
    constexpr int KC = KTOT / 32;
    __shared__ unsigned short As[64][136];   // row stride 272B: b128 frag reads conflict-free
    const int tid = threadIdx.x;
    const int wave = tid >> 6;
    const int lane = tid & 63;
    const int ln15 = lane & 15;
    const int quad = lane >> 4;
    const int m0 = blockIdx.x * 64;
    const int ntw = wave * NS;

    f32x4 acc[4][NS];
#pragma unroll
    for (int s = 0; s < 4; ++s)
#pragma unroll
        for (int h = 0; h < NS; ++h) acc[s][h] = (f32x4){0.f, 0.f, 0.f, 0.f};

    for (int kb = 0; kb < KTOT / 128; ++kb) {
        // stage 64x128 bf16 A chunk (rows padded in the buffers, so OOB rows read garbage)
#pragma unroll
        for (int i = 0; i < 4; ++i) {
            int idx = tid + i * 256;      // 16B-chunk index
            int r = idx >> 4;
            int c8 = (idx & 15) * 8;      // bf16 element col
            uint4 v = *(const uint4*)&A[(size_t)(m0 + r) * lda + kb * 128 + c8];
            *(uint4*)&As[r][c8] = v;
        }
        __syncthreads();
#pragma unroll
        for (int kc = 0; kc < 4; ++kc) {
            short8 af[4];
#pragma unroll
            for (int s = 0; s < 4; ++s)
                af[s] = *(const short8*)&As[s * 16 + ln15][kc * 32 + quad * 8];
            short8 bf[NS];
#pragma unroll
            for (int h = 0; h < NS; ++h) {
                int kcg = kb * 4 + kc;
                bf[h] = *(const short8*)&pW[((size_t)((ntw + h) * KC + kcg) * 64 + lane) * 8];
            }
#pragma unroll
            for (int s = 0; s < 4; ++s)
#pragma unroll
                for (int h = 0; h < NS; ++h)
                    acc[s][h] = __builtin_amdgcn_mfma_f32_16x16x32_bf16(
                        af[s], bf[h], acc[s][h], 0, 0, 0);
        }
        __syncthreads();
    }

    // epilogue: C/D layout col=lane&15, row=quad*4+reg
#pragma unroll
    for (int s = 0; s < 4; ++s) {
#pragma unroll
        for (int h = 0; h < NS; ++h) {
            int col = (ntw + h) * 16 + ln15;
            float bv = BIAS ? bias[col] : 0.f;
#pragma unroll
            for (int r = 0; r < 4; ++r) {
                int row = m0 + s * 16 + quad * 4 + r;
                if (row < M) {
                    float v = acc[s][h][r] + bv;
                    if (RELU) v = fmaxf(v, 0.f);
                    C[(size_t)row * ldc + col] = __float2bfloat16(v);
                }
            }
        }
    }
}

// ---------------- SpMM: out[node] = relu(sum_e val*support[col] + b), bf16 in/out ----------------
__global__ __launch_bounds__(256)
void spmm_kernel(const int* __restrict__ row_ptr, const int* __restrict__ ecol,
                 const float* __restrict__ eval, const __hip_bfloat16* __restrict__ support,
                 const float* __restrict__ bias, __hip_bfloat16* __restrict__ out,
                 int ldo, int n) {
    int t = threadIdx.x;
    int sub = t >> 5;
    int l = t & 31;
    int node = blockIdx.x * 8 + sub;
    if (node >= n) return;
    int start = row_ptr[node], end = row_ptr[node + 1];
    float4 acc = {0.f, 0.f, 0.f, 0.f};
    int p = start;
    for (; p + 2 <= end; p += 2) {
        int c0 = ecol[p], c1 = ecol[p + 1];
        float v0 = eval[p], v1 = eval[p + 1];
        ushort4 u0 = *(const ushort4*)&support[(size_t)c0 * 128 + l * 4];
        ushort4 u1 = *(const ushort4*)&support[(size_t)c1 * 128 + l * 4];
        acc.x += v0 * b2f(u0.x); acc.y += v0 * b2f(u0.y);
        acc.z += v0 * b2f(u0.z); acc.w += v0 * b2f(u0.w);
        acc.x += v1 * b2f(u1.x); acc.y += v1 * b2f(u1.y);
        acc.z += v1 * b2f(u1.z); acc.w += v1 * b2f(u1.w);
    }
    if (p < end) {
        int c0 = ecol[p];
        float v0 = eval[p];
        ushort4 u0 = *(const ushort4*)&support[(size_t)c0 * 128 + l * 4];
        acc.x += v0 * b2f(u0.x); acc.y += v0 * b2f(u0.y);
        acc.z += v0 * b2f(u0.z); acc.w += v0 * b2f(u0.w);
    }
    float4 b = *(const float4*)&bias[l * 4];
    __hip_bfloat16 o[4];
    o[0] = __float2bfloat16(fmaxf(acc.x + b.x, 0.f));
    o[1] = __float2bfloat16(fmaxf(acc.y + b.y, 0.f));
    o[2] = __float2bfloat16(fmaxf(acc.z + b.z, 0.f));
    o[3] = __float2bfloat16(fmaxf(acc.w + b.w, 0.f));
    *(ushort4*)&out[(size_t)node * ldo + l * 4] = *(ushort4*)&o[0];
}

// ---------------- final 64->2 layer (bf16 in, fp32 out) ----------------
__global__ __launch_bounds__(256)
void fc3_kernel(const __hip_bfloat16* __restrict__ h2, const float* __restrict__ W,
                const float* __restrict__ b, float* __restrict__ out, int M) {
    __shared__ float Ws[128];
    if (threadIdx.x < 128) Ws[threadIdx.x] = W[threadIdx.x];
    __syncthreads();
    int nid = blockIdx.x * blockDim.x + threadIdx.x;
    if (nid >= M) return;
    float a0 = b[0], a1 = b[1];
#pragma unroll
    for (int k8 = 0; k8 < 8; ++k8) {
        ushort4 u0 = *(const ushort4*)&h2[(size_t)nid * 64 + k8 * 8];
        ushort4 u1 = *(const ushort4*)&h2[(size_t)nid * 64 + k8 * 8 + 4];
        float f[8] = {b2f(u0.x), b2f(u0.y), b2f(u0.z), b2f(u0.w),
                      b2f(u1.x), b2f(u1.y), b2f(u1.z), b2f(u1.w)};
#pragma unroll
        for (int j = 0; j < 8; ++j) {
            int k = k8 * 8 + j;
            a0 += f[j] * Ws[k * 2 + 0];
            a1 += f[j] * Ws[k * 2 + 1];
        }
    }
    out[(size_t)nid * 2 + 0] = a0;
    out[(size_t)nid * 2 + 1] = a1;
}

extern "C" void kernel_launch(void* const* d_in, const int* in_sizes, int n_in,
                              void* d_out, int out_size, void* d_ws, size_t ws_size,
                              hipStream_t stream) {
    const int*   adj_row  = (const int*)d_in[0];
    const int*   adj_col  = (const int*)d_in[1];
    const float* adj_vals = (const float*)d_in[2];
    const float* x        = (const float*)d_in[3];
    const float* W1   = (const float*)d_in[5];
    const float* b1   = (const float*)d_in[6];
    const float* W2   = (const float*)d_in[7];
    const float* b2   = (const float*)d_in[8];
    const float* W3   = (const float*)d_in[9];
    const float* b3   = (const float*)d_in[10];
    const float* fcW1 = (const float*)d_in[11];
    const float* fcb1 = (const float*)d_in[12];
    const float* fcW2 = (const float*)d_in[13];
    const float* fcb2 = (const float*)d_in[14];
    const float* fcW3 = (const float*)d_in[15];
    const float* fcb3 = (const float*)d_in[16];
    float* out = (float*)d_out;

    const int N = N_NODES, E = N_EDGES;
    const int Mpad = 50048;  // 64-row pad: GEMM staging may read past M

    char* p = (char*)d_ws;
    auto alloc = [&](size_t bytes) {
        char* q = p;
        p += (bytes + 255) & ~(size_t)255;
        return q;
    };
    __hip_bfloat16* featb    = (__hip_bfloat16*)alloc((size_t)Mpad * 384 * 2); // g1|g2|g3
    __hip_bfloat16* xb       = (__hip_bfloat16*)alloc((size_t)Mpad * 128 * 2);
    __hip_bfloat16* supportb = (__hip_bfloat16*)alloc((size_t)Mpad * 128 * 2);
    __hip_bfloat16* pW1   = (__hip_bfloat16*)alloc(16384 * 2);
    __hip_bfloat16* pW2   = (__hip_bfloat16*)alloc(16384 * 2);
    __hip_bfloat16* pW3   = (__hip_bfloat16*)alloc(16384 * 2);
    __hip_bfloat16* pfcW1 = (__hip_bfloat16*)alloc(49152 * 2);
    __hip_bfloat16* pfcW2 = (__hip_bfloat16*)alloc(8192 * 2);
    int*   row_ptr = (int*)alloc((size_t)(N + 1) * 4);
    int*   cursor  = (int*)alloc((size_t)N * 4);
    int*   ecol    = (int*)alloc((size_t)E * 4);
    float* eval    = (float*)alloc((size_t)E * 4);
    __hip_bfloat16* h1b = supportb;  // supportb dead after 3rd spmm
    __hip_bfloat16* h2b = featb;     // featb dead after fc1

    // ---- CSR build ----
    hipMemsetAsync(cursor, 0, (size_t)N * 4, stream);
    hist_kernel<<<cdiv(E, 256), 256, 0, stream>>>(adj_row, cursor, E);
    scan_kernel<<<1, 1024, 0, stream>>>(cursor, row_ptr, N);
    hipMemsetAsync(cursor, 0, (size_t)N * 4, stream);
    scatter_kernel<<<cdiv(E, 256), 256, 0, stream>>>(adj_row, adj_col, adj_vals,
                                                     row_ptr, cursor, ecol, eval, E);

    // ---- converts & weight packing ----
    f2b_kernel<<<cdiv(N * 128 / 4, 256), 256, 0, stream>>>(x, xb, N * 128);
    pack_w_kernel<<<8, 256, 0, stream>>>(W1, pW1, 128, 128);
    pack_w_kernel<<<8, 256, 0, stream>>>(W2, pW2, 128, 128);
    pack_w_kernel<<<8, 256, 0, stream>>>(W3, pW3, 128, 128);
    pack_w_kernel<<<24, 256, 0, stream>>>(fcW1, pfcW1, 384, 128);
    pack_w_kernel<<<4, 256, 0, stream>>>(fcW2, pfcW2, 128, 64);

    const int gemmGrid = cdiv(N, 64);
    const int spmmGrid = cdiv(N, 8);

    // ---- GCN layer 1 ----
    mfma_gemm<128, 128, false, false><<<gemmGrid, 256, 0, stream>>>(
        xb, 128, pW1, nullptr, supportb, 128, N);
    spmm_kernel<<<spmmGrid, 256, 0, stream>>>(row_ptr, ecol, eval, supportb, b1,
                                              featb + 0, 384, N);
    // ---- GCN layer 2 ----
    mfma_gemm<128, 128, false, false><<<gemmGrid, 256, 0, stream>>>(
        featb + 0, 384, pW2, nullptr, supportb, 128, N);
    spmm_kernel<<<spmmGrid, 256, 0, stream>>>(row_ptr, ecol, eval, supportb, b2,
                                              featb + 128, 384, N);
    // ---- GCN layer 3 ----
    mfma_gemm<128, 128, false, false><<<gemmGrid, 256, 0, stream>>>(
        featb + 128, 384, pW3, nullptr, supportb, 128, N);
    spmm_kernel<<<spmmGrid, 256, 0, stream>>>(row_ptr, ecol, eval, supportb, b3,
                                              featb + 256, 384, N);

    // ---- fc1 ----
    mfma_gemm<384, 128, true, true><<<gemmGrid, 256, 0, stream>>>(
        featb, 384, pfcW1, fcb1, h1b, 128, N);
    // ---- fc2 ----
    mfma_gemm<128, 64, true, true><<<gemmGrid, 256, 0, stream>>>(
        h1b, 128, pfcW2, fcb2, h2b, 64, N);
    // ---- fc3 ----
    fc3_kernel<<<cdiv(N, 256), 256, 0, stream>>>(h2b, fcW3, fcb3, out, N);
}

// Round 5
// 379.189 us; speedup vs baseline: 1.9086x; 1.2151x over previous
//
#include <hip/hip_runtime.h>
#include <hip/hip_bf16.h>

#define N_NODES 50000
#define N_EDGES 800000

static inline int cdiv(int a, int b) { return (a + b - 1) / b; }

typedef __attribute__((ext_vector_type(8))) short short8;
typedef __attribute__((ext_vector_type(4))) float f32x4;

__device__ __forceinline__ float b2f(unsigned short u) {
    union { unsigned int i; float f; } c;
    c.i = ((unsigned int)u) << 16;
    return c.f;
}

// ---------------- CSR build ----------------

__global__ void hist_kernel(const int* __restrict__ row, int* __restrict__ counts, int E) {
    int e = blockIdx.x * 256 + threadIdx.x;
    if (e < E) atomicAdd(&counts[row[e]], 1);
}

// phase 1: 49 blocks x 1024 elems; local exclusive prefix into row_ptr, block total out
__global__ __launch_bounds__(256)
void scan1_kernel(const int* __restrict__ counts, int* __restrict__ row_ptr,
                  int* __restrict__ blocksums, int n) {
    __shared__ int s[256];
    int t = threadIdx.x;
    int base = blockIdx.x * 1024 + t * 4;
    int4 v = {0, 0, 0, 0};
    if (base + 3 < n) v = *(const int4*)&counts[base];
    else {
        if (base + 0 < n) v.x = counts[base + 0];
        if (base + 1 < n) v.y = counts[base + 1];
        if (base + 2 < n) v.z = counts[base + 2];
        if (base + 3 < n) v.w = counts[base + 3];
    }
    int sum = v.x + v.y + v.z + v.w;
    s[t] = sum;
    __syncthreads();
    for (int off = 1; off < 256; off <<= 1) {
        int u = (t >= off) ? s[t - off] : 0;
        __syncthreads();
        s[t] += u;
        __syncthreads();
    }
    int ex = s[t] - sum;
    int4 o;
    o.x = ex;
    o.y = ex + v.x;
    o.z = o.y + v.y;
    o.w = o.z + v.z;
    if (base + 3 < n) *(int4*)&row_ptr[base] = o;
    else {
        if (base + 0 < n) row_ptr[base + 0] = o.x;
        if (base + 1 < n) row_ptr[base + 1] = o.y;
        if (base + 2 < n) row_ptr[base + 2] = o.z;
        if (base + 3 < n) row_ptr[base + 3] = o.w;
    }
    if (t == 255) blocksums[blockIdx.x] = s[255];
}

// phase 2: single wave inclusive-scans <=64 block sums in place
__global__ __launch_bounds__(64)
void scan2_kernel(int* __restrict__ blocksums, int nb) {
    int t = threadIdx.x;
    int v = (t < nb) ? blocksums[t] : 0;
#pragma unroll
    for (int off = 1; off < 64; off <<= 1) {
        int u = __shfl_up(v, off);
        if (t >= off) v += u;
    }
    if (t < nb) blocksums[t] = v;
}

// phase 3: add block offsets; write row_ptr[n]
__global__ __launch_bounds__(256)
void scan3_kernel(int* __restrict__ row_ptr, const int* __restrict__ blocksums,
                  int n, int nb) {
    int t = threadIdx.x;
    int b = blockIdx.x;
    int off = (b == 0) ? 0 : blocksums[b - 1];
    int base = b * 1024 + t * 4;
    if (b > 0) {
        if (base + 3 < n) {
            int4 v = *(int4*)&row_ptr[base];
            v.x += off; v.y += off; v.z += off; v.w += off;
            *(int4*)&row_ptr[base] = v;
        } else {
            if (base + 0 < n) row_ptr[base + 0] += off;
            if (base + 1 < n) row_ptr[base + 1] += off;
            if (base + 2 < n) row_ptr[base + 2] += off;
            if (base + 3 < n) row_ptr[base + 3] += off;
        }
    }
    if (b == nb - 1 && t == 255) row_ptr[n] = blocksums[nb - 1];
}

__global__ void scatter_kernel(const int* __restrict__ row, const int* __restrict__ col,
                               const float* __restrict__ vals, const int* __restrict__ row_ptr,
                               int* __restrict__ cursor, int2* __restrict__ epack, int E) {
    int e = blockIdx.x * 256 + threadIdx.x;
    if (e < E) {
        int r = row[e];
        int pos = row_ptr[r] + atomicAdd(&cursor[r], 1);
        epack[pos] = make_int2(col[e], __float_as_int(vals[e]));
    }
}

// ---------------- converts / packing ----------------

__global__ void f2b_kernel(const float* __restrict__ in, __hip_bfloat16* __restrict__ out, int n) {
    int i = (blockIdx.x * 256 + threadIdx.x) * 4;
    if (i >= n) return;
    float4 v = *(const float4*)&in[i];
    __hip_bfloat16 h[4] = {__float2bfloat16(v.x), __float2bfloat16(v.y),
                           __float2bfloat16(v.z), __float2bfloat16(v.w)};
    *(ushort2*)&out[i] = *(ushort2*)&h[0];
    *(ushort2*)&out[i + 2] = *(ushort2*)&h[2];
}

// pack fp32 W[K,N] row-major into B-fragment order for mfma_f32_16x16x32_bf16:
// frag element j of lane l for (n-tile nt, k-chunk kc) = W[kc*32 + (l>>4)*8 + j][nt*16 + (l&15)]
__device__ __forceinline__ void pack_one(const float* __restrict__ W,
                                         __hip_bfloat16* __restrict__ out,
                                         int K, int N, int t) {
    int lane = t & 63;
    int kc = (t >> 6) % (K / 32);
    int nt = (t >> 6) / (K / 32);
    int kbase = kc * 32 + (lane >> 4) * 8;
    int col = nt * 16 + (lane & 15);
    __hip_bfloat16* dst = out + (size_t)t * 8;
#pragma unroll
    for (int j = 0; j < 8; ++j)
        dst[j] = __float2bfloat16(W[(size_t)(kbase + j) * N + col]);
}

// all five weights in one launch: blocks [0,8) W1, [8,16) W2, [16,24) W3,
// [24,48) fcW1 (K=384), [48,52) fcW2 (N=64)
__global__ __launch_bounds__(256)
void pack_all_kernel(const float* __restrict__ W1, const float* __restrict__ W2,
                     const float* __restrict__ W3, const float* __restrict__ fcW1,
                     const float* __restrict__ fcW2,
                     __hip_bfloat16* __restrict__ pW1, __hip_bfloat16* __restrict__ pW2,
                     __hip_bfloat16* __restrict__ pW3, __hip_bfloat16* __restrict__ pfcW1,
                     __hip_bfloat16* __restrict__ pfcW2) {
    int b = blockIdx.x;
    if (b < 8)       pack_one(W1,  pW1,  128, 128, b * 256 + threadIdx.x);
    else if (b < 16) pack_one(W2,  pW2,  128, 128, (b - 8) * 256 + threadIdx.x);
    else if (b < 24) pack_one(W3,  pW3,  128, 128, (b - 16) * 256 + threadIdx.x);
    else if (b < 48) pack_one(fcW1, pfcW1, 384, 128, (b - 24) * 256 + threadIdx.x);
    else             pack_one(fcW2, pfcW2, 128, 64, (b - 48) * 256 + threadIdx.x);
}

// ---------------- bf16 MFMA GEMM ----------------
template <int KTOT, int N, bool RELU, bool BIAS>
__global__ __launch_bounds__(256, 3)
void mfma_gemm(const __hip_bfloat16* __restrict__ A, int lda,
               const __hip_bfloat16* __restrict__ pW,
               const float* __restrict__ bias,
               __hip_bfloat16* __restrict__ C, int ldc, int M) {
    constexpr int NS = (N == 128) ? 2 : 1;
    constexpr int KC = KTOT / 32;
    __shared__ unsigned short As[64][136];   // row stride 272B: b128 frag reads conflict-free
    const int tid = threadIdx.x;
    const int wave = tid >> 6;
    const int lane = tid & 63;
    const int ln15 = lane & 15;
    const int quad = lane >> 4;
    const int m0 = blockIdx.x * 64;
    const int ntw = wave * NS;

    f32x4 acc[4][NS];
#pragma unroll
    for (int s = 0; s < 4; ++s)
#pragma unroll
        for (int h = 0; h < NS; ++h) acc[s][h] = (f32x4){0.f, 0.f, 0.f, 0.f};

    for (int kb = 0; kb < KTOT / 128; ++kb) {
#pragma unroll
        for (int i = 0; i < 4; ++i) {
            int idx = tid + i * 256;
            int r = idx >> 4;
            int c8 = (idx & 15) * 8;
            uint4 v = *(const uint4*)&A[(size_t)(m0 + r) * lda + kb * 128 + c8];
            *(uint4*)&As[r][c8] = v;
        }
        __syncthreads();
#pragma unroll
        for (int kc = 0; kc < 4; ++kc) {
            short8 af[4];
#pragma unroll
            for (int s = 0; s < 4; ++s)
                af[s] = *(const short8*)&As[s * 16 + ln15][kc * 32 + quad * 8];
            short8 bf[NS];
#pragma unroll
            for (int h = 0; h < NS; ++h) {
                int kcg = kb * 4 + kc;
                bf[h] = *(const short8*)&pW[((size_t)((ntw + h) * KC + kcg) * 64 + lane) * 8];
            }
#pragma unroll
            for (int s = 0; s < 4; ++s)
#pragma unroll
                for (int h = 0; h < NS; ++h)
                    acc[s][h] = __builtin_amdgcn_mfma_f32_16x16x32_bf16(
                        af[s], bf[h], acc[s][h], 0, 0, 0);
        }
        __syncthreads();
    }

#pragma unroll
    for (int s = 0; s < 4; ++s) {
#pragma unroll
        for (int h = 0; h < NS; ++h) {
            int col = (ntw + h) * 16 + ln15;
            float bv = BIAS ? bias[col] : 0.f;
#pragma unroll
            for (int r = 0; r < 4; ++r) {
                int row = m0 + s * 16 + quad * 4 + r;
                if (row < M) {
                    float v = acc[s][h][r] + bv;
                    if (RELU) v = fmaxf(v, 0.f);
                    C[(size_t)row * ldc + col] = __float2bfloat16(v);
                }
            }
        }
    }
}

// ---------------- SpMM ----------------
__global__ __launch_bounds__(256)
void spmm_kernel(const int* __restrict__ row_ptr, const int2* __restrict__ epack,
                 const __hip_bfloat16* __restrict__ support,
                 const float* __restrict__ bias, __hip_bfloat16* __restrict__ out,
                 int ldo, int n) {
    int t = threadIdx.x;
    int sub = t >> 5;
    int l = t & 31;
    int node = blockIdx.x * 8 + sub;
    if (node >= n) return;
    int start = row_ptr[node], end = row_ptr[node + 1];
    float4 acc = {0.f, 0.f, 0.f, 0.f};
    int p = start;
    for (; p + 2 <= end; p += 2) {
        int2 e0 = epack[p], e1 = epack[p + 1];
        float v0 = __int_as_float(e0.y), v1 = __int_as_float(e1.y);
        ushort4 u0 = *(const ushort4*)&support[(size_t)e0.x * 128 + l * 4];
        ushort4 u1 = *(const ushort4*)&support[(size_t)e1.x * 128 + l * 4];
        acc.x += v0 * b2f(u0.x); acc.y += v0 * b2f(u0.y);
        acc.z += v0 * b2f(u0.z); acc.w += v0 * b2f(u0.w);
        acc.x += v1 * b2f(u1.x); acc.y += v1 * b2f(u1.y);
        acc.z += v1 * b2f(u1.z); acc.w += v1 * b2f(u1.w);
    }
    if (p < end) {
        int2 e0 = epack[p];
        float v0 = __int_as_float(e0.y);
        ushort4 u0 = *(const ushort4*)&support[(size_t)e0.x * 128 + l * 4];
        acc.x += v0 * b2f(u0.x); acc.y += v0 * b2f(u0.y);
        acc.z += v0 * b2f(u0.z); acc.w += v0 * b2f(u0.w);
    }
    float4 b = *(const float4*)&bias[l * 4];
    __hip_bfloat16 o[4];
    o[0] = __float2bfloat16(fmaxf(acc.x + b.x, 0.f));
    o[1] = __float2bfloat16(fmaxf(acc.y + b.y, 0.f));
    o[2] = __float2bfloat16(fmaxf(acc.z + b.z, 0.f));
    o[3] = __float2bfloat16(fmaxf(acc.w + b.w, 0.f));
    *(ushort4*)&out[(size_t)node * ldo + l * 4] = *(ushort4*)&o[0];
}

// ---------------- final 64->2 layer (bf16 in, fp32 out) ----------------
__global__ __launch_bounds__(256)
void fc3_kernel(const __hip_bfloat16* __restrict__ h2, const float* __restrict__ W,
                const float* __restrict__ b, float* __restrict__ out, int M) {
    __shared__ float Ws[128];
    if (threadIdx.x < 128) Ws[threadIdx.x] = W[threadIdx.x];
    __syncthreads();
    int nid = blockIdx.x * blockDim.x + threadIdx.x;
    if (nid >= M) return;
    float a0 = b[0], a1 = b[1];
#pragma unroll
    for (int k8 = 0; k8 < 8; ++k8) {
        ushort4 u0 = *(const ushort4*)&h2[(size_t)nid * 64 + k8 * 8];
        ushort4 u1 = *(const ushort4*)&h2[(size_t)nid * 64 + k8 * 8 + 4];
        float f[8] = {b2f(u0.x), b2f(u0.y), b2f(u0.z), b2f(u0.w),
                      b2f(u1.x), b2f(u1.y), b2f(u1.z), b2f(u1.w)};
#pragma unroll
        for (int j = 0; j < 8; ++j) {
            int k = k8 * 8 + j;
            a0 += f[j] * Ws[k * 2 + 0];
            a1 += f[j] * Ws[k * 2 + 1];
        }
    }
    out[(size_t)nid * 2 + 0] = a0;
    out[(size_t)nid * 2 + 1] = a1;
}

extern "C" void kernel_launch(void* const* d_in, const int* in_sizes, int n_in,
                              void* d_out, int out_size, void* d_ws, size_t ws_size,
                              hipStream_t stream) {
    const int*   adj_row  = (const int*)d_in[0];
    const int*   adj_col  = (const int*)d_in[1];
    const float* adj_vals = (const float*)d_in[2];
    const float* x        = (const float*)d_in[3];
    const float* W1   = (const float*)d_in[5];
    const float* b1   = (const float*)d_in[6];
    const float* W2   = (const float*)d_in[7];
    const float* b2   = (const float*)d_in[8];
    const float* W3   = (const float*)d_in[9];
    const float* b3   = (const float*)d_in[10];
    const float* fcW1 = (const float*)d_in[11];
    const float* fcb1 = (const float*)d_in[12];
    const float* fcW2 = (const float*)d_in[13];
    const float* fcb2 = (const float*)d_in[14];
    const float* fcW3 = (const float*)d_in[15];
    const float* fcb3 = (const float*)d_in[16];
    float* out = (float*)d_out;

    const int N = N_NODES, E = N_EDGES;
    const int Mpad = 50048;
    const int NB = cdiv(N, 1024);   // 49 scan blocks

    char* p = (char*)d_ws;
    auto alloc = [&](size_t bytes) {
        char* q = p;
        p += (bytes + 255) & ~(size_t)255;
        return q;
    };
    __hip_bfloat16* featb    = (__hip_bfloat16*)alloc((size_t)Mpad * 384 * 2);
    __hip_bfloat16* xb       = (__hip_bfloat16*)alloc((size_t)Mpad * 128 * 2);
    __hip_bfloat16* supportb = (__hip_bfloat16*)alloc((size_t)Mpad * 128 * 2);
    __hip_bfloat16* pW1   = (__hip_bfloat16*)alloc(16384 * 2);
    __hip_bfloat16* pW2   = (__hip_bfloat16*)alloc(16384 * 2);
    __hip_bfloat16* pW3   = (__hip_bfloat16*)alloc(16384 * 2);
    __hip_bfloat16* pfcW1 = (__hip_bfloat16*)alloc(49152 * 2);
    __hip_bfloat16* pfcW2 = (__hip_bfloat16*)alloc(8192 * 2);
    int*   row_ptr   = (int*)alloc((size_t)(N + 1) * 4);
    int*   cursor    = (int*)alloc((size_t)(N + 4) * 4);
    int*   blocksums = (int*)alloc(64 * 4);
    int2*  epack     = (int2*)alloc((size_t)E * 8);
    __hip_bfloat16* h1b = supportb;  // supportb dead after 3rd spmm
    __hip_bfloat16* h2b = featb;     // featb dead after fc1

    // ---- CSR build ----
    hipMemsetAsync(cursor, 0, (size_t)N * 4, stream);
    hist_kernel<<<cdiv(E, 256), 256, 0, stream>>>(adj_row, cursor, E);
    scan1_kernel<<<NB, 256, 0, stream>>>(cursor, row_ptr, blocksums, N);
    scan2_kernel<<<1, 64, 0, stream>>>(blocksums, NB);
    scan3_kernel<<<NB, 256, 0, stream>>>(row_ptr, blocksums, N, NB);
    hipMemsetAsync(cursor, 0, (size_t)N * 4, stream);
    scatter_kernel<<<cdiv(E, 256), 256, 0, stream>>>(adj_row, adj_col, adj_vals,
                                                     row_ptr, cursor, epack, E);

    // ---- converts & weight packing ----
    f2b_kernel<<<cdiv(N * 128 / 4, 256), 256, 0, stream>>>(x, xb, N * 128);
    pack_all_kernel<<<52, 256, 0, stream>>>(W1, W2, W3, fcW1, fcW2,
                                            pW1, pW2, pW3, pfcW1, pfcW2);

    const int gemmGrid = cdiv(N, 64);
    const int spmmGrid = cdiv(N, 8);

    // ---- GCN layer 1 ----
    mfma_gemm<128, 128, false, false><<<gemmGrid, 256, 0, stream>>>(
        xb, 128, pW1, nullptr, supportb, 128, N);
    spmm_kernel<<<spmmGrid, 256, 0, stream>>>(row_ptr, epack, supportb, b1,
                                              featb + 0, 384, N);
    // ---- GCN layer 2 ----
    mfma_gemm<128, 128, false, false><<<gemmGrid, 256, 0, stream>>>(
        featb + 0, 384, pW2, nullptr, supportb, 128, N);
    spmm_kernel<<<spmmGrid, 256, 0, stream>>>(row_ptr, epack, supportb, b2,
                                              featb + 128, 384, N);
    // ---- GCN layer 3 ----
    mfma_gemm<128, 128, false, false><<<gemmGrid, 256, 0, stream>>>(
        featb + 128, 384, pW3, nullptr, supportb, 128, N);
    spmm_kernel<<<spmmGrid, 256, 0, stream>>>(row_ptr, epack, supportb, b3,
                                              featb + 256, 384, N);

    // ---- fc1 ----
    mfma_gemm<384, 128, true, true><<<gemmGrid, 256, 0, stream>>>(
        featb, 384, pfcW1, fcb1, h1b, 128, N);
    // ---- fc2 ----
    mfma_gemm<128, 64, true, true><<<gemmGrid, 256, 0, stream>>>(
        h1b, 128, pfcW2, fcb2, h2b, 64, N);
    // ---- fc3 ----
    fc3_kernel<<<cdiv(N, 256), 256, 0, stream>>>(h2b, fcW3, fcb3, out, N);
}

// Round 6
// 338.258 us; speedup vs baseline: 2.1395x; 1.1210x over previous
//
#include <hip/hip_runtime.h>
#include <hip/hip_bf16.h>

#define N_NODES 50000
#define N_EDGES 800000
#define NBK 391          // ceil(50000/128) row buckets of 128 rows

static inline int cdiv(int a, int b) { return (a + b - 1) / b; }

typedef __attribute__((ext_vector_type(8))) short short8;
typedef __attribute__((ext_vector_type(4))) float f32x4;

__device__ __forceinline__ float b2f(unsigned short u) {
    union { unsigned int i; float f; } c;
    c.i = ((unsigned int)u) << 16;
    return c.f;
}

// ---------------- CSR build ----------------

__global__ void hist_kernel(const int* __restrict__ row, int* __restrict__ counts, int E) {
    int e = blockIdx.x * 256 + threadIdx.x;
    if (e < E) atomicAdd(&counts[row[e]], 1);
}

__global__ __launch_bounds__(256)
void scan1_kernel(const int* __restrict__ counts, int* __restrict__ row_ptr,
                  int* __restrict__ blocksums, int n) {
    __shared__ int s[256];
    int t = threadIdx.x;
    int base = blockIdx.x * 1024 + t * 4;
    int4 v = {0, 0, 0, 0};
    if (base + 3 < n) v = *(const int4*)&counts[base];
    else {
        if (base + 0 < n) v.x = counts[base + 0];
        if (base + 1 < n) v.y = counts[base + 1];
        if (base + 2 < n) v.z = counts[base + 2];
        if (base + 3 < n) v.w = counts[base + 3];
    }
    int sum = v.x + v.y + v.z + v.w;
    s[t] = sum;
    __syncthreads();
    for (int off = 1; off < 256; off <<= 1) {
        int u = (t >= off) ? s[t - off] : 0;
        __syncthreads();
        s[t] += u;
        __syncthreads();
    }
    int ex = s[t] - sum;
    int4 o;
    o.x = ex;
    o.y = ex + v.x;
    o.z = o.y + v.y;
    o.w = o.z + v.z;
    if (base + 3 < n) *(int4*)&row_ptr[base] = o;
    else {
        if (base + 0 < n) row_ptr[base + 0] = o.x;
        if (base + 1 < n) row_ptr[base + 1] = o.y;
        if (base + 2 < n) row_ptr[base + 2] = o.z;
        if (base + 3 < n) row_ptr[base + 3] = o.w;
    }
    if (t == 255) blocksums[blockIdx.x] = s[255];
}

__global__ __launch_bounds__(64)
void scan2_kernel(int* __restrict__ blocksums, int nb) {
    int t = threadIdx.x;
    int v = (t < nb) ? blocksums[t] : 0;
#pragma unroll
    for (int off = 1; off < 64; off <<= 1) {
        int u = __shfl_up(v, off);
        if (t >= off) v += u;
    }
    if (t < nb) blocksums[t] = v;
}

__global__ __launch_bounds__(256)
void scan3_kernel(int* __restrict__ row_ptr, const int* __restrict__ blocksums,
                  int n, int nb) {
    int t = threadIdx.x;
    int b = blockIdx.x;
    int off = (b == 0) ? 0 : blocksums[b - 1];
    int base = b * 1024 + t * 4;
    if (b > 0) {
        if (base + 3 < n) {
            int4 v = *(int4*)&row_ptr[base];
            v.x += off; v.y += off; v.z += off; v.w += off;
            *(int4*)&row_ptr[base] = v;
        } else {
            if (base + 0 < n) row_ptr[base + 0] += off;
            if (base + 1 < n) row_ptr[base + 1] += off;
            if (base + 2 < n) row_ptr[base + 2] += off;
            if (base + 3 < n) row_ptr[base + 3] += off;
        }
    }
    if (b == nb - 1 && t == 255) row_ptr[n] = blocksums[nb - 1];
}

// bucket cursors start at each bucket's CSR region base
__global__ void binit_kernel(const int* __restrict__ row_ptr, int* __restrict__ bcursor) {
    int b = blockIdx.x * 256 + threadIdx.x;
    if (b < NBK) bcursor[b] = row_ptr[b << 7];
}

// Phase A: bin edges by row>>7 into bucket-grouped tmp (CSR address space).
// Per-block LDS hist -> one global atomic per (block,bucket) -> run writes
// are time/XCD-local so L2 merges lines (kills the 8x write amplification).
__global__ __launch_bounds__(256)
void binA_kernel(const int* __restrict__ row, const int* __restrict__ col,
                 const float* __restrict__ vals, int* __restrict__ bcursor,
                 int2* __restrict__ tmp, int E) {
    __shared__ int hist[NBK];
    __shared__ int base[NBK];
    const int CH = 4096;
    int e0 = blockIdx.x * CH;
    for (int i = threadIdx.x; i < NBK; i += 256) hist[i] = 0;
    __syncthreads();
    for (int i = threadIdx.x; i < CH; i += 256) {
        int e = e0 + i;
        if (e < E) atomicAdd(&hist[row[e] >> 7], 1);
    }
    __syncthreads();
    for (int i = threadIdx.x; i < NBK; i += 256) {
        int c = hist[i];
        base[i] = (c > 0) ? atomicAdd(&bcursor[i], c) : 0;
        hist[i] = 0;                       // reuse as local rank counter
    }
    __syncthreads();
    for (int i = threadIdx.x; i < CH; i += 256) {
        int e = e0 + i;
        if (e < E) {
            int r = row[e];
            int b = r >> 7;
            int rk = atomicAdd(&hist[b], 1);
            // pack local row (7b) + col (16b) in .x, val bits in .y
            tmp[base[b] + rk] = make_int2(((r & 127) << 16) | col[e],
                                          __float_as_int(vals[e]));
        }
    }
}

// Phase B: one block per bucket; exact CSR placement with LDS row cursors.
// Writes confined to the bucket's ~16KB single-owner region.
__global__ __launch_bounds__(256)
void binB_kernel(const int2* __restrict__ tmp, const int* __restrict__ row_ptr,
                 int2* __restrict__ epack, int N) {
    int b = blockIdx.x;
    int r0 = b << 7;
    int nr = N - r0; if (nr > 128) nr = 128;
    __shared__ int cur[128];
    int t = threadIdx.x;
    if (t < 128) cur[t] = (t < nr) ? row_ptr[r0 + t] : 0;
    __syncthreads();
    int start = row_ptr[r0];
    int end = row_ptr[r0 + nr];
    for (int i = start + t; i < end; i += 256) {
        int2 v = tmp[i];
        int rl = v.x >> 16;
        int c = v.x & 0xffff;
        int pos = atomicAdd(&cur[rl], 1);
        epack[pos] = make_int2(c, v.y);
    }
}

// ---------------- converts / packing ----------------

__global__ void f2b_kernel(const float* __restrict__ in, __hip_bfloat16* __restrict__ out, int n) {
    int i = (blockIdx.x * 256 + threadIdx.x) * 4;
    if (i >= n) return;
    float4 v = *(const float4*)&in[i];
    __hip_bfloat16 h[4] = {__float2bfloat16(v.x), __float2bfloat16(v.y),
                           __float2bfloat16(v.z), __float2bfloat16(v.w)};
    *(ushort2*)&out[i] = *(ushort2*)&h[0];
    *(ushort2*)&out[i + 2] = *(ushort2*)&h[2];
}

__device__ __forceinline__ void pack_one(const float* __restrict__ W,
                                         __hip_bfloat16* __restrict__ out,
                                         int K, int N, int t) {
    int lane = t & 63;
    int kc = (t >> 6) % (K / 32);
    int nt = (t >> 6) / (K / 32);
    int kbase = kc * 32 + (lane >> 4) * 8;
    int col = nt * 16 + (lane & 15);
    __hip_bfloat16* dst = out + (size_t)t * 8;
#pragma unroll
    for (int j = 0; j < 8; ++j)
        dst[j] = __float2bfloat16(W[(size_t)(kbase + j) * N + col]);
}

__global__ __launch_bounds__(256)
void pack_all_kernel(const float* __restrict__ W1, const float* __restrict__ W2,
                     const float* __restrict__ W3, const float* __restrict__ fcW1,
                     const float* __restrict__ fcW2,
                     __hip_bfloat16* __restrict__ pW1, __hip_bfloat16* __restrict__ pW2,
                     __hip_bfloat16* __restrict__ pW3, __hip_bfloat16* __restrict__ pfcW1,
                     __hip_bfloat16* __restrict__ pfcW2) {
    int b = blockIdx.x;
    if (b < 8)       pack_one(W1,  pW1,  128, 128, b * 256 + threadIdx.x);
    else if (b < 16) pack_one(W2,  pW2,  128, 128, (b - 8) * 256 + threadIdx.x);
    else if (b < 24) pack_one(W3,  pW3,  128, 128, (b - 16) * 256 + threadIdx.x);
    else if (b < 48) pack_one(fcW1, pfcW1, 384, 128, (b - 24) * 256 + threadIdx.x);
    else             pack_one(fcW2, pfcW2, 128, 64, (b - 48) * 256 + threadIdx.x);
}

// ---------------- bf16 MFMA GEMM (layer GEMMs) ----------------
template <int KTOT, int N, bool RELU, bool BIAS>
__global__ __launch_bounds__(256, 3)
void mfma_gemm(const __hip_bfloat16* __restrict__ A, int lda,
               const __hip_bfloat16* __restrict__ pW,
               const float* __restrict__ bias,
               __hip_bfloat16* __restrict__ C, int ldc, int M) {
    constexpr int NS = (N == 128) ? 2 : 1;
    constexpr int KC = KTOT / 32;
    __shared__ unsigned short As[64][136];
    const int tid = threadIdx.x;
    const int wave = tid >> 6;
    const int lane = tid & 63;
    const int ln15 = lane & 15;
    const int quad = lane >> 4;
    const int m0 = blockIdx.x * 64;
    const int ntw = wave * NS;

    f32x4 acc[4][NS];
#pragma unroll
    for (int s = 0; s < 4; ++s)
#pragma unroll
        for (int h = 0; h < NS; ++h) acc[s][h] = (f32x4){0.f, 0.f, 0.f, 0.f};

    for (int kb = 0; kb < KTOT / 128; ++kb) {
#pragma unroll
        for (int i = 0; i < 4; ++i) {
            int idx = tid + i * 256;
            int r = idx >> 4;
            int c8 = (idx & 15) * 8;
            uint4 v = *(const uint4*)&A[(size_t)(m0 + r) * lda + kb * 128 + c8];
            *(uint4*)&As[r][c8] = v;
        }
        __syncthreads();
#pragma unroll
        for (int kc = 0; kc < 4; ++kc) {
            short8 af[4];
#pragma unroll
            for (int s = 0; s < 4; ++s)
                af[s] = *(const short8*)&As[s * 16 + ln15][kc * 32 + quad * 8];
            short8 bf[NS];
#pragma unroll
            for (int h = 0; h < NS; ++h) {
                int kcg = kb * 4 + kc;
                bf[h] = *(const short8*)&pW[((size_t)((ntw + h) * KC + kcg) * 64 + lane) * 8];
            }
#pragma unroll
            for (int s = 0; s < 4; ++s)
#pragma unroll
                for (int h = 0; h < NS; ++h)
                    acc[s][h] = __builtin_amdgcn_mfma_f32_16x16x32_bf16(
                        af[s], bf[h], acc[s][h], 0, 0, 0);
        }
        __syncthreads();
    }

#pragma unroll
    for (int s = 0; s < 4; ++s) {
#pragma unroll
        for (int h = 0; h < NS; ++h) {
            int col = (ntw + h) * 16 + ln15;
            float bv = BIAS ? bias[col] : 0.f;
#pragma unroll
            for (int r = 0; r < 4; ++r) {
                int row = m0 + s * 16 + quad * 4 + r;
                if (row < M) {
                    float v = acc[s][h][r] + bv;
                    if (RELU) v = fmaxf(v, 0.f);
                    C[(size_t)row * ldc + col] = __float2bfloat16(v);
                }
            }
        }
    }
}

// ---------------- fused FC head: fc1 -> fc2 -> fc3, h1/h2 never leave LDS ----------------
__global__ __launch_bounds__(256, 3)
void fc123_kernel(const __hip_bfloat16* __restrict__ featb,   // lda 384
                  const __hip_bfloat16* __restrict__ pfcW1,   // packed K=384,N=128
                  const float* __restrict__ fcb1,
                  const __hip_bfloat16* __restrict__ pfcW2,   // packed K=128,N=64
                  const float* __restrict__ fcb2,
                  const float* __restrict__ fcW3, const float* __restrict__ fcb3,
                  float* __restrict__ out, int M) {
    __shared__ unsigned short As[64][136];
    __shared__ float w3s[128];
    __shared__ float b3s[2];
    const int tid = threadIdx.x;
    const int wave = tid >> 6;
    const int lane = tid & 63;
    const int ln15 = lane & 15;
    const int quad = lane >> 4;
    const int m0 = blockIdx.x * 64;
    if (tid < 128) w3s[tid] = fcW3[tid];
    if (tid < 2) b3s[tid] = fcb3[tid];

    // ---- fc1: K=384, N=128 (NS=2 per wave) ----
    f32x4 acc[4][2];
#pragma unroll
    for (int s = 0; s < 4; ++s)
#pragma unroll
        for (int h = 0; h < 2; ++h) acc[s][h] = (f32x4){0.f, 0.f, 0.f, 0.f};
    for (int kb = 0; kb < 3; ++kb) {
#pragma unroll
        for (int i = 0; i < 4; ++i) {
            int idx = tid + i * 256;
            int r = idx >> 4;
            int c8 = (idx & 15) * 8;
            uint4 v = *(const uint4*)&featb[(size_t)(m0 + r) * 384 + kb * 128 + c8];
            *(uint4*)&As[r][c8] = v;
        }
        __syncthreads();
#pragma unroll
        for (int kc = 0; kc < 4; ++kc) {
            short8 af[4];
#pragma unroll
            for (int s = 0; s < 4; ++s)
                af[s] = *(const short8*)&As[s * 16 + ln15][kc * 32 + quad * 8];
            short8 bf[2];
#pragma unroll
            for (int h = 0; h < 2; ++h) {
                int kcg = kb * 4 + kc;
                bf[h] = *(const short8*)&pfcW1[((size_t)((wave * 2 + h) * 12 + kcg) * 64 + lane) * 8];
            }
#pragma unroll
            for (int s = 0; s < 4; ++s)
#pragma unroll
                for (int h = 0; h < 2; ++h)
                    acc[s][h] = __builtin_amdgcn_mfma_f32_16x16x32_bf16(
                        af[s], bf[h], acc[s][h], 0, 0, 0);
        }
        __syncthreads();
    }
    // h1 tile (relu+bias) -> As (bf16)
#pragma unroll
    for (int s = 0; s < 4; ++s)
#pragma unroll
        for (int h = 0; h < 2; ++h) {
            int col = (wave * 2 + h) * 16 + ln15;
            float bv = fcb1[col];
#pragma unroll
            for (int r = 0; r < 4; ++r) {
                int row = s * 16 + quad * 4 + r;
                __hip_bfloat16 hv = __float2bfloat16(fmaxf(acc[s][h][r] + bv, 0.f));
                As[row][col] = *(unsigned short*)&hv;
            }
        }
    __syncthreads();

    // ---- fc2: K=128, N=64 (wave's n-tile = wave) ----
    f32x4 acc2[4];
#pragma unroll
    for (int s = 0; s < 4; ++s) acc2[s] = (f32x4){0.f, 0.f, 0.f, 0.f};
#pragma unroll
    for (int kc = 0; kc < 4; ++kc) {
        short8 af[4];
#pragma unroll
        for (int s = 0; s < 4; ++s)
            af[s] = *(const short8*)&As[s * 16 + ln15][kc * 32 + quad * 8];
        short8 bfw = *(const short8*)&pfcW2[((size_t)(wave * 4 + kc) * 64 + lane) * 8];
#pragma unroll
        for (int s = 0; s < 4; ++s)
            acc2[s] = __builtin_amdgcn_mfma_f32_16x16x32_bf16(af[s], bfw, acc2[s], 0, 0, 0);
    }
    __syncthreads();
    // h2 tile (relu+bias) -> As (64 cols used)
    {
        int col2 = wave * 16 + ln15;
        float bv = fcb2[col2];
#pragma unroll
        for (int s = 0; s < 4; ++s)
#pragma unroll
            for (int r = 0; r < 4; ++r) {
                int row = s * 16 + quad * 4 + r;
                __hip_bfloat16 hv = __float2bfloat16(fmaxf(acc2[s][r] + bv, 0.f));
                As[row][col2] = *(unsigned short*)&hv;
            }
    }
    __syncthreads();

    // ---- fc3: 64 -> 2 ----
    if (tid < 128) {
        int row = tid >> 1, cls = tid & 1;
        int grow = m0 + row;
        if (grow < M) {
            float a = b3s[cls];
#pragma unroll
            for (int k = 0; k < 64; ++k)
                a += b2f(As[row][k]) * w3s[k * 2 + cls];
            out[(size_t)grow * 2 + cls] = a;
        }
    }
}

// ---------------- SpMM ----------------
__global__ __launch_bounds__(256)
void spmm_kernel(const int* __restrict__ row_ptr, const int2* __restrict__ epack,
                 const __hip_bfloat16* __restrict__ support,
                 const float* __restrict__ bias, __hip_bfloat16* __restrict__ out,
                 int ldo, int n) {
    int t = threadIdx.x;
    int sub = t >> 5;
    int l = t & 31;
    int node = blockIdx.x * 8 + sub;
    if (node >= n) return;
    int start = row_ptr[node], end = row_ptr[node + 1];
    float4 acc = {0.f, 0.f, 0.f, 0.f};
    int p = start;
    for (; p + 2 <= end; p += 2) {
        int2 e0 = epack[p], e1 = epack[p + 1];
        float v0 = __int_as_float(e0.y), v1 = __int_as_float(e1.y);
        ushort4 u0 = *(const ushort4*)&support[(size_t)e0.x * 128 + l * 4];
        ushort4 u1 = *(const ushort4*)&support[(size_t)e1.x * 128 + l * 4];
        acc.x += v0 * b2f(u0.x); acc.y += v0 * b2f(u0.y);
        acc.z += v0 * b2f(u0.z); acc.w += v0 * b2f(u0.w);
        acc.x += v1 * b2f(u1.x); acc.y += v1 * b2f(u1.y);
        acc.z += v1 * b2f(u1.z); acc.w += v1 * b2f(u1.w);
    }
    if (p < end) {
        int2 e0 = epack[p];
        float v0 = __int_as_float(e0.y);
        ushort4 u0 = *(const ushort4*)&support[(size_t)e0.x * 128 + l * 4];
        acc.x += v0 * b2f(u0.x); acc.y += v0 * b2f(u0.y);
        acc.z += v0 * b2f(u0.z); acc.w += v0 * b2f(u0.w);
    }
    float4 b = *(const float4*)&bias[l * 4];
    __hip_bfloat16 o[4];
    o[0] = __float2bfloat16(fmaxf(acc.x + b.x, 0.f));
    o[1] = __float2bfloat16(fmaxf(acc.y + b.y, 0.f));
    o[2] = __float2bfloat16(fmaxf(acc.z + b.z, 0.f));
    o[3] = __float2bfloat16(fmaxf(acc.w + b.w, 0.f));
    *(ushort4*)&out[(size_t)node * ldo + l * 4] = *(ushort4*)&o[0];
}

extern "C" void kernel_launch(void* const* d_in, const int* in_sizes, int n_in,
                              void* d_out, int out_size, void* d_ws, size_t ws_size,
                              hipStream_t stream) {
    const int*   adj_row  = (const int*)d_in[0];
    const int*   adj_col  = (const int*)d_in[1];
    const float* adj_vals = (const float*)d_in[2];
    const float* x        = (const float*)d_in[3];
    const float* W1   = (const float*)d_in[5];
    const float* b1   = (const float*)d_in[6];
    const float* W2   = (const float*)d_in[7];
    const float* b2   = (const float*)d_in[8];
    const float* W3   = (const float*)d_in[9];
    const float* b3   = (const float*)d_in[10];
    const float* fcW1 = (const float*)d_in[11];
    const float* fcb1 = (const float*)d_in[12];
    const float* fcW2 = (const float*)d_in[13];
    const float* fcb2 = (const float*)d_in[14];
    const float* fcW3 = (const float*)d_in[15];
    const float* fcb3 = (const float*)d_in[16];
    float* out = (float*)d_out;

    const int N = N_NODES, E = N_EDGES;
    const int Mpad = 50048;
    const int NB = cdiv(N, 1024);

    char* p = (char*)d_ws;
    auto alloc = [&](size_t bytes) {
        char* q = p;
        p += (bytes + 255) & ~(size_t)255;
        return q;
    };
    __hip_bfloat16* featb    = (__hip_bfloat16*)alloc((size_t)Mpad * 384 * 2);
    __hip_bfloat16* xb       = (__hip_bfloat16*)alloc((size_t)Mpad * 128 * 2);
    __hip_bfloat16* supportb = (__hip_bfloat16*)alloc((size_t)Mpad * 128 * 2);
    __hip_bfloat16* pW1   = (__hip_bfloat16*)alloc(16384 * 2);
    __hip_bfloat16* pW2   = (__hip_bfloat16*)alloc(16384 * 2);
    __hip_bfloat16* pW3   = (__hip_bfloat16*)alloc(16384 * 2);
    __hip_bfloat16* pfcW1 = (__hip_bfloat16*)alloc(49152 * 2);
    __hip_bfloat16* pfcW2 = (__hip_bfloat16*)alloc(8192 * 2);
    int*   row_ptr   = (int*)alloc((size_t)(N + 1) * 4);
    int*   cursor    = (int*)alloc((size_t)(N + 4) * 4);
    int*   blocksums = (int*)alloc(64 * 4);
    int*   bcursor   = (int*)alloc((size_t)NBK * 4);
    int2*  epack     = (int2*)alloc((size_t)E * 8);
    // tmp aliases the tail of featb: featb is dead until spmm1, which runs
    // after binB has consumed tmp.
    int2*  tmp = (int2*)(featb + (size_t)Mpad * 384 - (size_t)E * 4);

    // ---- CSR build (binned two-phase scatter) ----
    hipMemsetAsync(cursor, 0, (size_t)N * 4, stream);
    hist_kernel<<<cdiv(E, 256), 256, 0, stream>>>(adj_row, cursor, E);
    scan1_kernel<<<NB, 256, 0, stream>>>(cursor, row_ptr, blocksums, N);
    scan2_kernel<<<1, 64, 0, stream>>>(blocksums, NB);
    scan3_kernel<<<NB, 256, 0, stream>>>(row_ptr, blocksums, N, NB);
    binit_kernel<<<cdiv(NBK, 256), 256, 0, stream>>>(row_ptr, bcursor);
    binA_kernel<<<cdiv(E, 4096), 256, 0, stream>>>(adj_row, adj_col, adj_vals,
                                                   bcursor, tmp, E);
    binB_kernel<<<NBK, 256, 0, stream>>>(tmp, row_ptr, epack, N);

    // ---- converts & weight packing ----
    f2b_kernel<<<cdiv(N * 128 / 4, 256), 256, 0, stream>>>(x, xb, N * 128);
    pack_all_kernel<<<52, 256, 0, stream>>>(W1, W2, W3, fcW1, fcW2,
                                            pW1, pW2, pW3, pfcW1, pfcW2);

    const int gemmGrid = cdiv(N, 64);
    const int spmmGrid = cdiv(N, 8);

    // ---- GCN layer 1 ----
    mfma_gemm<128, 128, false, false><<<gemmGrid, 256, 0, stream>>>(
        xb, 128, pW1, nullptr, supportb, 128, N);
    spmm_kernel<<<spmmGrid, 256, 0, stream>>>(row_ptr, epack, supportb, b1,
                                              featb + 0, 384, N);
    // ---- GCN layer 2 ----
    mfma_gemm<128, 128, false, false><<<gemmGrid, 256, 0, stream>>>(
        featb + 0, 384, pW2, nullptr, supportb, 128, N);
    spmm_kernel<<<spmmGrid, 256, 0, stream>>>(row_ptr, epack, supportb, b2,
                                              featb + 128, 384, N);
    // ---- GCN layer 3 ----
    mfma_gemm<128, 128, false, false><<<gemmGrid, 256, 0, stream>>>(
        featb + 128, 384, pW3, nullptr, supportb, 128, N);
    spmm_kernel<<<spmmGrid, 256, 0, stream>>>(row_ptr, epack, supportb, b3,
                                              featb + 256, 384, N);

    // ---- fused FC head ----
    fc123_kernel<<<gemmGrid, 256, 0, stream>>>(featb, pfcW1, fcb1, pfcW2, fcb2,
                                               fcW3, fcb3, out, N);
}